// Round 10
// baseline (97.262 us; speedup 1.0000x reference)
//
#include <hip/hip_runtime.h>
#include <hip/hip_fp16.h>

namespace {
constexpr int kB = 2, kH = 16, kS = 2048, kD = 64, kBH = kB * kH;
constexpr int BQ = 128, BKV = 64;
constexpr int NQT = kS / BQ;   // 16

typedef _Float16 f16x8 __attribute__((ext_vector_type(8)));
typedef _Float16 f16x4 __attribute__((ext_vector_type(4)));
typedef __fp16 fp16x2 __attribute__((ext_vector_type(2)));
typedef float f32x16 __attribute__((ext_vector_type(16)));
typedef float f32x4 __attribute__((ext_vector_type(4)));
typedef unsigned int u32;

// Q prescale: 1/sqrt(64) * log2(e) -> softmax done in exp2 domain.
constexpr float kQScale = 0.125f * 1.4426950408889634f;

__device__ __forceinline__ u32 pkrtz(float a, float b) {
  union { fp16x2 h; u32 u; } c;
  c.h = __builtin_amdgcn_cvt_pkrtz(a, b);
  return c.u;
}

// ---- preprocess 1: per-batch mask scan -> compaction index + bias + NT ----
__global__ __launch_bounds__(256) void scan_kernel(const int* __restrict__ M,
                                                   int* __restrict__ Idx,
                                                   float* __restrict__ BiasC,
                                                   int* __restrict__ NTarr) {
  const int b = blockIdx.x;
  const int tid = threadIdx.x;
  __shared__ int part[256];
  __shared__ int nvs;
  int m[8], sum = 0;
#pragma unroll
  for (int i = 0; i < 8; ++i) {
    m[i] = M[b * kS + tid * 8 + i];
    sum += m[i] ? 1 : 0;
  }
  part[tid] = sum;
  __syncthreads();
  for (int off = 1; off < 256; off <<= 1) {
    int v = (tid >= off) ? part[tid - off] : 0;
    __syncthreads();
    part[tid] += v;
    __syncthreads();
  }
  int run = part[tid] - sum;  // exclusive prefix
#pragma unroll
  for (int i = 0; i < 8; ++i)
    if (m[i]) Idx[b * kS + run++] = tid * 8 + i;
  if (tid == 255) nvs = part[255];
  __syncthreads();
  const int Nv = nvs;
  int NT = (Nv + 63) >> 6;
  if (NT == 0) NT = 1;
  const int pad = NT * 64;
  for (int j = Nv + tid; j < pad; j += 256) Idx[b * kS + j] = 0;
#pragma unroll
  for (int i = 0; i < 8; ++i) {
    const int j = tid * 8 + i;
    BiasC[b * kS + j] = (j < Nv) ? 0.f : -1e30f;
  }
  if (tid == 0) NTarr[b] = NT;
}

// ---- preprocess 2: gather+convert K fp32 -> compacted f16 [bh][j][d] ----
__global__ __launch_bounds__(256) void gather_k_kernel(
    const float* __restrict__ K, const int* __restrict__ Idx,
    const int* __restrict__ NTarr, _Float16* __restrict__ Kc) {
  const int e = blockIdx.x * 256 + threadIdx.x;  // [0, kBH*2048*8)
  const int bh = e >> 14;
  const int rem = e & 16383;
  const int j = rem >> 3;
  const int d0 = (rem & 7) << 3;
  const int b = bh >> 4;
  if (j >= NTarr[b] * 64) return;
  const int src = Idx[b * kS + j];
  const float* p = K + ((size_t)bh * kS + src) * kD + d0;
  float4 x = *(const float4*)p;
  float4 y = *(const float4*)(p + 4);
  f16x8 o;
  o[0] = (_Float16)x.x; o[1] = (_Float16)x.y; o[2] = (_Float16)x.z; o[3] = (_Float16)x.w;
  o[4] = (_Float16)y.x; o[5] = (_Float16)y.y; o[6] = (_Float16)y.z; o[7] = (_Float16)y.w;
  *(f16x8*)(Kc + ((size_t)bh * kS + j) * kD + d0) = o;
}

// ---- preprocess 3: gather V rows -> compacted transposed f16 [bh][d][j] ----
__global__ __launch_bounds__(256) void gather_vt_kernel(
    const float* __restrict__ V, const int* __restrict__ Idx,
    const int* __restrict__ NTarr, _Float16* __restrict__ Vtc) {
  __shared__ _Float16 Vl[64 * 68];
  __shared__ int ridx[64];
  const int tid = threadIdx.x;
  const int bh = blockIdx.x >> 5;
  const int jt = blockIdx.x & 31;
  const int b = bh >> 4;
  if (jt >= NTarr[b]) return;
  if (tid < 64) ridx[tid] = Idx[b * kS + jt * 64 + tid];
  __syncthreads();
  const float* vb = V + (size_t)bh * kS * kD;
#pragma unroll
  for (int i = 0; i < 4; ++i) {
    int off = (tid + 256 * i) * 4;
    int r = off >> 6, c = off & 63;
    float4 x = *(const float4*)(vb + (size_t)ridx[r] * kD + c);
    Vl[(c + 0) * 68 + r] = (_Float16)x.x;
    Vl[(c + 1) * 68 + r] = (_Float16)x.y;
    Vl[(c + 2) * 68 + r] = (_Float16)x.z;
    Vl[(c + 3) * 68 + r] = (_Float16)x.w;
  }
  __syncthreads();
  const int d = tid >> 2, c0 = (tid & 3) * 16;
  _Float16* op = Vtc + ((size_t)bh * kD + d) * kS + jt * 64 + c0;
#pragma unroll
  for (int j = 0; j < 4; ++j)
    *(f16x4*)(op + 4 * j) = *(const f16x4*)(Vl + d * 68 + c0 + 4 * j);
}

// ------- main: direct global->reg fragments, NO LDS / barriers in K-loop ----
// Compacted KV is L2-resident; each lane's fragment is a contiguous 16B read.
// V(t) issued at iter top (consumed after softmax, ~700cyc lead); K(t+1)
// register-double-buffered via unroll-2 ping-pong. Waves free-run.
__global__ __launch_bounds__(256, 2) void fattn_d(
    const _Float16* __restrict__ Kc, const _Float16* __restrict__ Vtc,
    const float* __restrict__ Q, const float* __restrict__ BiasC,
    const int* __restrict__ NTarr, float* __restrict__ O) {
  __shared__ float Os[64 * 68];  // epilogue transpose only

  const int tid = threadIdx.x;
  const int lane = tid & 63;
  const int w = tid >> 6;    // wave 0..3
  const int q = lane & 31;   // qrow within wave tile
  const int h = lane >> 5;   // half 0/1

  // XCD-aware bijective swizzle (gridDim % 8 == 0).
  const int bid = blockIdx.x;
  const int cpx = gridDim.x >> 3;
  const int sbid = (bid & 7) * cpx + (bid >> 3);
  const int bh = sbid >> 4;
  const int qt = sbid & 15;
  const int q0 = qt * BQ;
  const int b = bh >> 4;  // H=16
  const int NT = NTarr[b];

  // Q fragments (B-operand), pre-scaled into exp2 domain.
  f16x8 qf[4];
  {
    const float* qp = Q + ((size_t)bh * kS + q0 + w * 32 + q) * kD;
#pragma unroll
    for (int dc = 0; dc < 4; ++dc) {
      const float* p = qp + dc * 16 + h * 8;
      float4 x = *(const float4*)p;
      float4 y = *(const float4*)(p + 4);
      f16x8 a;
      a[0] = (_Float16)(x.x * kQScale); a[1] = (_Float16)(x.y * kQScale);
      a[2] = (_Float16)(x.z * kQScale); a[3] = (_Float16)(x.w * kQScale);
      a[4] = (_Float16)(y.x * kQScale); a[5] = (_Float16)(y.y * kQScale);
      a[6] = (_Float16)(y.z * kQScale); a[7] = (_Float16)(y.w * kQScale);
      qf[dc] = a;
    }
  }

  f32x16 oa[2];
#pragma unroll
  for (int i = 0; i < 16; ++i) { oa[0][i] = 0.f; oa[1][i] = 0.f; }
  // m_run floor -30 (log2 units): exp2(bias - m_run) = 0 for pad keys.
  float m_run = -30.f, l_run = 0.f;

  const _Float16* kb = Kc + (size_t)bh * kS * kD;
  const _Float16* vb = Vtc + (size_t)bh * kD * kS;
  const float* mpc = BiasC + b * kS;

  // per-lane fragment bases
  const _Float16* kbase0 = kb + (q + 0) * 64 + h * 8;        // mt=0 rows
  const _Float16* kbase1 = kb + (q + 32) * 64 + h * 8;       // mt=1 rows
  const _Float16* vbase0 = vb + (size_t)(q + 0) * kS + h * 8;   // md=0 d-rows
  const _Float16* vbase1 = vb + (size_t)(q + 32) * kS + h * 8;  // md=1 d-rows

  f16x8 kA[8], kB[8], vr[8];
  auto loadK = [&](int t, f16x8 (&kr)[8]) {
    const int off = t * 4096;  // 64 rows * 64 f16
#pragma unroll
    for (int dc = 0; dc < 4; ++dc) {
      kr[dc] = *(const f16x8*)(kbase0 + off + dc * 16);
      kr[4 + dc] = *(const f16x8*)(kbase1 + off + dc * 16);
    }
  };
  auto loadV = [&](int t) {
    const int off = t * 64;
#pragma unroll
    for (int kk = 0; kk < 4; ++kk) {
      vr[kk] = *(const f16x8*)(vbase0 + off + kk * 16);
      vr[4 + kk] = *(const f16x8*)(vbase1 + off + kk * 16);
    }
  };

  auto body = [&](int t, f16x8 (&kcur)[8], f16x8 (&knext)[8], bool pf) {
    loadV(t);                    // in flight across QK+softmax
    if (pf) loadK(t + 1, knext); // in flight across the whole iter

    // ---- QK^T (swapped), bias C-init from global (L2-hot) ----
    // s[mt][4g+j] has key = t*64 + mt*32 + 8g + 4h + j, qrow = q
    const float* mb = mpc + t * 64;
    f32x16 s[2];
    __builtin_amdgcn_s_setprio(1);
#pragma unroll
    for (int mt = 0; mt < 2; ++mt) {
      f32x16 z;
#pragma unroll
      for (int g = 0; g < 4; ++g) {
        f32x4 mv = *(const f32x4*)(mb + mt * 32 + 8 * g + 4 * h);
        z[4 * g + 0] = mv[0]; z[4 * g + 1] = mv[1];
        z[4 * g + 2] = mv[2]; z[4 * g + 3] = mv[3];
      }
#pragma unroll
      for (int dc = 0; dc < 4; ++dc)
        z = __builtin_amdgcn_mfma_f32_32x32x16_f16(kcur[mt * 4 + dc], qf[dc], z, 0, 0, 0);
      s[mt] = z;
    }
    __builtin_amdgcn_s_setprio(0);

    // ---- tile max (tree) + cross-half combine ----
    float tm[16];
#pragma unroll
    for (int i = 0; i < 16; ++i) tm[i] = fmaxf(s[0][i], s[1][i]);
#pragma unroll
    for (int st = 8; st > 0; st >>= 1)
#pragma unroll
      for (int i = 0; i < st; ++i) tm[i] = fmaxf(tm[i], tm[i + st]);
    const float mx = fmaxf(tm[0], __shfl_xor(tm[0], 32));

    // ---- defer-max (T13): only rescale when max grew by > 8 (log2) ----
    if (__any(mx > m_run + 8.f)) {
      const float mnew = fmaxf(m_run, mx);
      const float corr = __builtin_amdgcn_exp2f(m_run - mnew);
      m_run = mnew;
      l_run *= corr;
#pragma unroll
      for (int mt = 0; mt < 2; ++mt)
#pragma unroll
        for (int r = 0; r < 16; ++r) oa[mt][r] *= corr;
    }
    const float negm = -m_run;

    // ---- p = exp2(s - m); tree sum ----
#pragma unroll
    for (int mt = 0; mt < 2; ++mt)
#pragma unroll
      for (int r = 0; r < 16; ++r)
        s[mt][r] = __builtin_amdgcn_exp2f(s[mt][r] + negm);
    float tsum[16];
#pragma unroll
    for (int i = 0; i < 16; ++i) tsum[i] = s[0][i] + s[1][i];
#pragma unroll
    for (int st = 8; st > 0; st >>= 1)
#pragma unroll
      for (int i = 0; i < st; ++i) tsum[i] += tsum[i + st];
    l_run += tsum[0] + __shfl_xor(tsum[0], 32);

    // ---- pack P to f16 pairs ----
    u32 pkA_[2][4], pkB_[2][4];
#pragma unroll
    for (int mt = 0; mt < 2; ++mt)
#pragma unroll
      for (int g = 0; g < 4; ++g) {
        pkA_[mt][g] = pkrtz(s[mt][4 * g + 0], s[mt][4 * g + 1]);
        pkB_[mt][g] = pkrtz(s[mt][4 * g + 2], s[mt][4 * g + 3]);
      }

    // ---- PV (swapped): oa[md] += V^T * P ----
    __builtin_amdgcn_s_setprio(1);
#pragma unroll
    for (int kk = 0; kk < 4; ++kk) {
      const int e = kk & 1, mt = kk >> 1;
      u32 crossA = __shfl_xor(h ? pkA_[mt][2 * e] : pkA_[mt][2 * e + 1], 32);
      u32 crossB = __shfl_xor(h ? pkB_[mt][2 * e] : pkB_[mt][2 * e + 1], 32);
      union { u32 u[4]; f16x8 v; } pb;
      pb.u[0] = h ? crossA : pkA_[mt][2 * e];
      pb.u[1] = h ? crossB : pkB_[mt][2 * e];
      pb.u[2] = h ? pkA_[mt][2 * e + 1] : crossA;
      pb.u[3] = h ? pkB_[mt][2 * e + 1] : crossB;
#pragma unroll
      for (int md = 0; md < 2; ++md)
        oa[md] = __builtin_amdgcn_mfma_f32_32x32x16_f16(vr[md * 4 + kk], pb.v, oa[md], 0, 0, 0);
    }
    __builtin_amdgcn_s_setprio(0);
  };

  // ---- K-loop: no barriers; reg ping-pong for K ----
  loadK(0, kA);
  int t = 0;
  while (t + 2 <= NT) {
    body(t, kA, kB, true);
    body(t + 1, kB, kA, t + 2 < NT);
    t += 2;
  }
  if (t < NT) body(t, kA, kB, false);

  // ---- epilogue: normalize, transpose via LDS, coalesced store ----
  const float inv = 1.f / l_run;
#pragma unroll
  for (int ph = 0; ph < 2; ++ph) {
    __syncthreads();
    if ((w >> 1) == ph) {
#pragma unroll
      for (int mt = 0; mt < 2; ++mt)
#pragma unroll
        for (int r = 0; r < 16; ++r) {
          int d = mt * 32 + (r & 3) + 8 * (r >> 2) + 4 * h;
          Os[((w & 1) * 32 + q) * 68 + d] = oa[mt][r] * inv;
        }
    }
    __syncthreads();
    {
      const int row = tid >> 2, cb = (tid & 3) * 16;
      float* op = O + ((size_t)bh * kS + q0 + ph * 64 + row) * kD + cb;
      const float* sp = Os + row * 68 + cb;
#pragma unroll
      for (int j = 0; j < 4; ++j) *(float4*)(op + 4 * j) = *(const float4*)(sp + 4 * j);
    }
  }
}

// ---------------- fallback (round-1 kernel) if ws is too small -------------
__device__ __forceinline__ int swz(int row, int colh) {
  return row * 64 + (colh ^ ((row & 7) << 3));
}

__global__ __launch_bounds__(256, 4) void fattn_fallback(
    const float* __restrict__ Q, const float* __restrict__ K,
    const float* __restrict__ V, const int* __restrict__ M,
    float* __restrict__ O) {
  __shared__ __align__(16) _Float16 Kl[64 * 64];
  __shared__ __align__(16) _Float16 Vtl[64 * 64];
  __shared__ __align__(16) _Float16 Pl[64 * 64];
  __shared__ float mbl[64];

  const int tid = threadIdx.x;
  const int lane = tid & 63;
  const int w = tid >> 6;
  const int lr = lane & 15;
  const int hg = lane >> 4;
  const int NQT1 = kS / 64;
  const int bh = blockIdx.x / NQT1;
  const int qt = blockIdx.x % NQT1;
  const int b = bh / kH;
  const int q0 = qt * 64;

  f16x8 aq[2];
  {
    const int row = q0 + w * 16 + lr;
    const float* qp = Q + ((size_t)bh * kS + row) * kD;
#pragma unroll
    for (int kf = 0; kf < 2; ++kf) {
      const float* p = qp + kf * 32 + hg * 8;
      float4 x = *(const float4*)(p);
      float4 y = *(const float4*)(p + 4);
      f16x8 a;
      a[0] = (_Float16)(x.x * 0.125f); a[1] = (_Float16)(x.y * 0.125f);
      a[2] = (_Float16)(x.z * 0.125f); a[3] = (_Float16)(x.w * 0.125f);
      a[4] = (_Float16)(y.x * 0.125f); a[5] = (_Float16)(y.y * 0.125f);
      a[6] = (_Float16)(y.z * 0.125f); a[7] = (_Float16)(y.w * 0.125f);
      aq[kf] = a;
    }
  }

  f32x4 oacc[4];
#pragma unroll
  for (int c = 0; c < 4; ++c) { oacc[c][0]=0.f; oacc[c][1]=0.f; oacc[c][2]=0.f; oacc[c][3]=0.f; }
  float m_run[4], l_run[4];
#pragma unroll
  for (int r = 0; r < 4; ++r) { m_run[r] = -1e30f; l_run[r] = 0.f; }

  const float* kb = K + (size_t)bh * kS * kD;
  const float* vb = V + (size_t)bh * kS * kD;
  const int* mbp = M + b * kS;

  for (int t0 = 0; t0 < kS; t0 += 64) {
    __syncthreads();
#pragma unroll
    for (int i = 0; i < 4; ++i) {
      const int off = (tid + 256 * i) * 4;
      const int row = off >> 6;
      const int col = off & 63;
      float4 kx = *(const float4*)(kb + (size_t)(t0 + row) * kD + col);
      f16x4 hk;
      hk[0] = (_Float16)kx.x; hk[1] = (_Float16)kx.y;
      hk[2] = (_Float16)kx.z; hk[3] = (_Float16)kx.w;
      *(f16x4*)(Kl + swz(row, col)) = hk;
      float4 vx = *(const float4*)(vb + (size_t)(t0 + row) * kD + col);
      Vtl[swz(col + 0, row)] = (_Float16)vx.x;
      Vtl[swz(col + 1, row)] = (_Float16)vx.y;
      Vtl[swz(col + 2, row)] = (_Float16)vx.z;
      Vtl[swz(col + 3, row)] = (_Float16)vx.w;
    }
    if (tid < 64) mbl[tid] = mbp[t0 + tid] ? 0.f : -1e30f;
    __syncthreads();

    f32x4 s[4];
#pragma unroll
    for (int c = 0; c < 4; ++c) {
      f32x4 z; z[0]=0.f; z[1]=0.f; z[2]=0.f; z[3]=0.f;
#pragma unroll
      for (int kf = 0; kf < 2; ++kf) {
        f16x8 bk = *(const f16x8*)(Kl + swz(c * 16 + lr, kf * 32 + hg * 8));
        z = __builtin_amdgcn_mfma_f32_16x16x32_f16(aq[kf], bk, z, 0, 0, 0);
      }
      const float mval = mbl[c * 16 + lr];
#pragma unroll
      for (int r = 0; r < 4; ++r) z[r] += mval;
      s[c] = z;
    }

    float tmax[4];
#pragma unroll
    for (int r = 0; r < 4; ++r)
      tmax[r] = fmaxf(fmaxf(s[0][r], s[1][r]), fmaxf(s[2][r], s[3][r]));
#pragma unroll
    for (int off = 1; off < 16; off <<= 1)
#pragma unroll
      for (int r = 0; r < 4; ++r) tmax[r] = fmaxf(tmax[r], __shfl_xor(tmax[r], off));

    float mnew[4], corr[4], tsum[4];
#pragma unroll
    for (int r = 0; r < 4; ++r) {
      mnew[r] = fmaxf(m_run[r], tmax[r]);
      corr[r] = __expf(m_run[r] - mnew[r]);
      m_run[r] = mnew[r];
      tsum[r] = 0.f;
    }
#pragma unroll
    for (int c = 0; c < 4; ++c)
#pragma unroll
      for (int r = 0; r < 4; ++r) {
        const float p = __expf(s[c][r] - mnew[r]);
        tsum[r] += p;
        Pl[swz(w * 16 + hg * 4 + r, c * 16 + lr)] = (_Float16)p;
      }
#pragma unroll
    for (int off = 1; off < 16; off <<= 1)
#pragma unroll
      for (int r = 0; r < 4; ++r) tsum[r] += __shfl_xor(tsum[r], off);
#pragma unroll
    for (int r = 0; r < 4; ++r) l_run[r] = l_run[r] * corr[r] + tsum[r];
#pragma unroll
    for (int c = 0; c < 4; ++c)
#pragma unroll
      for (int r = 0; r < 4; ++r) oacc[c][r] *= corr[r];

#pragma unroll
    for (int kf = 0; kf < 2; ++kf) {
      f16x8 pa = *(const f16x8*)(Pl + swz(w * 16 + lr, kf * 32 + hg * 8));
#pragma unroll
      for (int cd = 0; cd < 4; ++cd) {
        f16x8 vbf = *(const f16x8*)(Vtl + swz(cd * 16 + lr, kf * 32 + hg * 8));
        oacc[cd] = __builtin_amdgcn_mfma_f32_16x16x32_f16(pa, vbf, oacc[cd], 0, 0, 0);
      }
    }
  }

#pragma unroll
  for (int r = 0; r < 4; ++r) {
    const float inv = 1.f / l_run[r];
    const int row = q0 + w * 16 + hg * 4 + r;
    float* op = O + ((size_t)bh * kS + row) * kD;
#pragma unroll
    for (int cd = 0; cd < 4; ++cd) op[cd * 16 + lr] = oacc[cd][r] * inv;
  }
}
}  // namespace

extern "C" void kernel_launch(void* const* d_in, const int* in_sizes, int n_in,
                              void* d_out, int out_size, void* d_ws, size_t ws_size,
                              hipStream_t stream) {
  (void)in_sizes; (void)n_in; (void)out_size;
  const float* q = (const float*)d_in[0];
  const float* k = (const float*)d_in[1];
  const float* v = (const float*)d_in[2];
  const int* m = (const int*)d_in[3];
  float* o = (float*)d_out;

  const size_t elems = (size_t)kBH * kS * kD;  // 4.19M
  const size_t need = 2 * elems * sizeof(_Float16)        // Kc + Vtc
                    + (size_t)kB * kS * sizeof(int)       // Idx
                    + (size_t)kB * kS * sizeof(float)     // BiasC
                    + 256;                                // NTarr (padded)

  if (ws_size >= need) {
    _Float16* Kc = (_Float16*)d_ws;
    _Float16* Vtc = Kc + elems;
    int* Idx = (int*)(Vtc + elems);
    float* BiasC = (float*)(Idx + (size_t)kB * kS);
    int* NTarr = (int*)(BiasC + (size_t)kB * kS);
    hipLaunchKernelGGL(scan_kernel, dim3(kB), dim3(256), 0, stream, m, Idx, BiasC, NTarr);
    hipLaunchKernelGGL(gather_k_kernel, dim3((kBH * kS * 8) / 256), dim3(256), 0, stream,
                       k, Idx, NTarr, Kc);
    hipLaunchKernelGGL(gather_vt_kernel, dim3(kBH * (kS / 64)), dim3(256), 0, stream,
                       v, Idx, NTarr, Vtc);
    hipLaunchKernelGGL(fattn_d, dim3(kBH * NQT), dim3(256), 0, stream,
                       Kc, Vtc, q, BiasC, NTarr, o);
  } else {
    hipLaunchKernelGGL(fattn_fallback, dim3(kBH * (kS / 64)), dim3(256), 0, stream,
                       q, k, v, m, o);
  }
}

// Round 11
// 63.050 us; speedup vs baseline: 1.5426x; 1.5426x over previous
//
#include <hip/hip_runtime.h>
#include <hip/hip_fp16.h>

namespace {
constexpr int kB = 2, kH = 16, kS = 2048, kD = 64, kBH = kB * kH;
constexpr int BQ = 64, BKV = 64;
constexpr int NQT = kS / BQ;   // 32

typedef _Float16 f16x8 __attribute__((ext_vector_type(8)));
typedef _Float16 f16x4 __attribute__((ext_vector_type(4)));
typedef __fp16 fp16x2 __attribute__((ext_vector_type(2)));
typedef float f32x16 __attribute__((ext_vector_type(16)));
typedef float f32x4 __attribute__((ext_vector_type(4)));
typedef unsigned int u32;

// Q prescale: 1/sqrt(64) * log2(e) -> softmax done in exp2 domain.
constexpr float kQScale = 0.125f * 1.4426950408889634f;

// Packed LDS tile: 64 logical rows x 64 f16 -> 32 prows x 128 halfwords.
__device__ __forceinline__ int paddr(int row, int col) {
  const int prow = row >> 1;
  return prow * 128 + ((((row & 1) << 6) | col) ^ ((prow & 15) << 3));
}

__device__ __forceinline__ u32 pkrtz(float a, float b) {
  union { fp16x2 h; u32 u; } c;
  c.h = __builtin_amdgcn_cvt_pkrtz(a, b);
  return c.u;
}

// ---- preprocess 1: per-batch mask scan -> compaction index + bias + NT ----
// NT is forced EVEN so the main kernel can split tiles across two wave-pairs.
__global__ __launch_bounds__(256) void scan_kernel(const int* __restrict__ M,
                                                   int* __restrict__ Idx,
                                                   float* __restrict__ BiasC,
                                                   int* __restrict__ NTarr) {
  const int b = blockIdx.x;
  const int tid = threadIdx.x;
  __shared__ int part[256];
  __shared__ int nvs;
  int m[8], sum = 0;
#pragma unroll
  for (int i = 0; i < 8; ++i) {
    m[i] = M[b * kS + tid * 8 + i];
    sum += m[i] ? 1 : 0;
  }
  part[tid] = sum;
  __syncthreads();
  for (int off = 1; off < 256; off <<= 1) {
    int v = (tid >= off) ? part[tid - off] : 0;
    __syncthreads();
    part[tid] += v;
    __syncthreads();
  }
  int run = part[tid] - sum;  // exclusive prefix
#pragma unroll
  for (int i = 0; i < 8; ++i)
    if (m[i]) Idx[b * kS + run++] = tid * 8 + i;
  if (tid == 255) nvs = part[255];
  __syncthreads();
  const int Nv = nvs;
  int NT = (Nv + 63) >> 6;
  if (NT == 0) NT = 1;
  NT += (NT & 1);  // even (<= 32 since kS/64 = 32)
  const int pad = NT * 64;
  for (int j = Nv + tid; j < pad; j += 256) Idx[b * kS + j] = 0;
#pragma unroll
  for (int i = 0; i < 8; ++i) {
    const int j = tid * 8 + i;
    BiasC[b * kS + j] = (j < Nv) ? 0.f : -1e30f;
  }
  if (tid == 0) NTarr[b] = NT;
}

// ---- preprocess 2: gather+convert K fp32 -> compacted f16 [bh][j][d] ----
__global__ __launch_bounds__(256) void gather_k_kernel(
    const float* __restrict__ K, const int* __restrict__ Idx,
    const int* __restrict__ NTarr, _Float16* __restrict__ Kc) {
  const int e = blockIdx.x * 256 + threadIdx.x;  // [0, kBH*2048*8)
  const int bh = e >> 14;
  const int rem = e & 16383;
  const int j = rem >> 3;
  const int d0 = (rem & 7) << 3;
  const int b = bh >> 4;
  if (j >= NTarr[b] * 64) return;
  const int src = Idx[b * kS + j];
  const float* p = K + ((size_t)bh * kS + src) * kD + d0;
  float4 x = *(const float4*)p;
  float4 y = *(const float4*)(p + 4);
  f16x8 o;
  o[0] = (_Float16)x.x; o[1] = (_Float16)x.y; o[2] = (_Float16)x.z; o[3] = (_Float16)x.w;
  o[4] = (_Float16)y.x; o[5] = (_Float16)y.y; o[6] = (_Float16)y.z; o[7] = (_Float16)y.w;
  *(f16x8*)(Kc + ((size_t)bh * kS + j) * kD + d0) = o;
}

// ---- preprocess 3: gather V rows -> compacted transposed f16 [bh][d][j] ----
__global__ __launch_bounds__(256) void gather_vt_kernel(
    const float* __restrict__ V, const int* __restrict__ Idx,
    const int* __restrict__ NTarr, _Float16* __restrict__ Vtc) {
  __shared__ _Float16 Vl[64 * 68];
  __shared__ int ridx[64];
  const int tid = threadIdx.x;
  const int bh = blockIdx.x >> 5;
  const int jt = blockIdx.x & 31;
  const int b = bh >> 4;
  if (jt >= NTarr[b]) return;
  if (tid < 64) ridx[tid] = Idx[b * kS + jt * 64 + tid];
  __syncthreads();
  const float* vb = V + (size_t)bh * kS * kD;
#pragma unroll
  for (int i = 0; i < 4; ++i) {
    int off = (tid + 256 * i) * 4;
    int r = off >> 6, c = off & 63;
    float4 x = *(const float4*)(vb + (size_t)ridx[r] * kD + c);
    Vl[(c + 0) * 68 + r] = (_Float16)x.x;
    Vl[(c + 1) * 68 + r] = (_Float16)x.y;
    Vl[(c + 2) * 68 + r] = (_Float16)x.z;
    Vl[(c + 3) * 68 + r] = (_Float16)x.w;
  }
  __syncthreads();
  const int d = tid >> 2, c0 = (tid & 3) * 16;
  _Float16* op = Vtc + ((size_t)bh * kD + d) * kS + jt * 64 + c0;
#pragma unroll
  for (int j = 0; j < 4; ++j)
    *(f16x4*)(op + 4 * j) = *(const f16x4*)(Vl + d * 68 + c0 + 4 * j);
}

// ------- main: in-block split-K. 4 waves; pair0 (w0,w1) = KV tiles
// [0,NT/2), pair1 (w2,w3) = [NT/2,NT), same 64 q-rows. Each pair has its
// own dbuf staging (R9/R5 loop body). LDS merge at the end; no merge kernel.
__global__ __launch_bounds__(256, 2) void fattn_m(
    const _Float16* __restrict__ Kc, const _Float16* __restrict__ Vtc,
    const float* __restrict__ Q, const float* __restrict__ BiasC,
    const int* __restrict__ NTarr, float* __restrict__ O) {
  // [pair0: K dbuf 16K | V dbuf 16K][pair1: same] | bias [2pair][2buf][64]
  // epilogue overlays: Os f32[64][68] @0; O1 f32[32][128] @32768; ml @49152
  __shared__ __align__(16) char smem[66560];

  const int tid = threadIdx.x;
  const int lane = tid & 63;
  const int q = lane & 31;   // qrow within wave tile
  const int h = lane >> 5;   // half 0/1
  const int pr = tid >> 7;        // pair 0/1 (KV half)
  const int pw = (tid >> 6) & 1;  // wave within pair -> q-row offset

  // XCD-aware bijective swizzle (gridDim = 1024, %8 == 0).
  const int bid = blockIdx.x;
  const int cpx = gridDim.x >> 3;
  const int sbid = (bid & 7) * cpx + (bid >> 3);
  const int bh = sbid >> 5;
  const int qt = sbid & 31;
  const int q0 = qt * BQ;
  const int b = bh >> 4;  // H=16
  const int NT = NTarr[b];     // even
  const int NTh = NT >> 1;
  const int g0 = pr * NTh;     // this pair's first tile

  _Float16* Kl = (_Float16*)(smem + pr * 32768);
  _Float16* Vl = (_Float16*)(smem + pr * 32768 + 16384);
  float* mbl = (float*)(smem + 65536 + pr * 512);  // [2buf][64]

  // Q fragments (B-operand), pre-scaled into exp2 domain.
  f16x8 qf[4];
  {
    const float* qp = Q + ((size_t)bh * kS + q0 + pw * 32 + q) * kD;
#pragma unroll
    for (int dc = 0; dc < 4; ++dc) {
      const float* p = qp + dc * 16 + h * 8;
      float4 x = *(const float4*)p;
      float4 y = *(const float4*)(p + 4);
      f16x8 a;
      a[0] = (_Float16)(x.x * kQScale); a[1] = (_Float16)(x.y * kQScale);
      a[2] = (_Float16)(x.z * kQScale); a[3] = (_Float16)(x.w * kQScale);
      a[4] = (_Float16)(y.x * kQScale); a[5] = (_Float16)(y.y * kQScale);
      a[6] = (_Float16)(y.z * kQScale); a[7] = (_Float16)(y.w * kQScale);
      qf[dc] = a;
    }
  }

  f32x16 oa[2];
#pragma unroll
  for (int i = 0; i < 16; ++i) { oa[0][i] = 0.f; oa[1][i] = 0.f; }
  float m_run = -30.f, l_run = 0.f;

  const _Float16* kb = Kc + (size_t)bh * kS * kD;
  const _Float16* vb = Vtc + (size_t)bh * kD * kS;
  const float* mpc = BiasC + b * kS;

  // staging geometry: 128 threads/pair; thread -> (row, 32-col half)
  const int ptid = tid & 127;
  const int sr = ptid >> 1, scb = (ptid & 1) * 32;
  int adr[4];
#pragma unroll
  for (int c = 0; c < 4; ++c) adr[c] = paddr(sr, scb + 8 * c);

  f16x8 nk[4], nv[4];
  float nmb = 0.f;
  auto loadT = [&](int g) {
    const _Float16* kp = kb + (size_t)(g * 64 + sr) * kD + scb;
    const _Float16* vp = vb + (size_t)sr * kS + g * 64 + scb;
#pragma unroll
    for (int c = 0; c < 4; ++c) {
      nk[c] = *(const f16x8*)(kp + 8 * c);
      nv[c] = *(const f16x8*)(vp + 8 * c);
    }
    if (ptid < 64) nmb = mpc[g * 64 + ptid];
  };
  auto writeT = [&](int buf) {
    _Float16* kd = Kl + buf * 4096;
    _Float16* vd = Vl + buf * 4096;
#pragma unroll
    for (int c = 0; c < 4; ++c) {
      *(f16x8*)(kd + adr[c]) = nk[c];
      *(f16x8*)(vd + adr[c]) = nv[c];
    }
    if (ptid < 64) mbl[buf * 64 + ptid] = nmb;
  };

  // prologue: stage this pair's tile 0
  loadT(g0);
  writeT(0);
  __syncthreads();

  int cur = 0;
  for (int i = 0; i < NTh; ++i) {
    const bool pf = (i + 1 < NTh);
    if (pf) loadT(g0 + i + 1);  // T14: in flight across compute

    const _Float16* kd = Kl + cur * 4096;
    const _Float16* vd = Vl + cur * 4096;
    const float* mb = mbl + cur * 64;

    // ---- QK^T (swapped), bias folded in as the MFMA C-init ----
    f32x16 s[2];
    __builtin_amdgcn_s_setprio(1);
#pragma unroll
    for (int mt = 0; mt < 2; ++mt) {
      f32x16 z;
#pragma unroll
      for (int g = 0; g < 4; ++g) {
        f32x4 mv = *(const f32x4*)(mb + mt * 32 + 8 * g + 4 * h);
        z[4 * g + 0] = mv[0]; z[4 * g + 1] = mv[1];
        z[4 * g + 2] = mv[2]; z[4 * g + 3] = mv[3];
      }
#pragma unroll
      for (int dc = 0; dc < 4; ++dc) {
        f16x8 kf = *(const f16x8*)(kd + paddr(mt * 32 + q, dc * 16 + h * 8));
        z = __builtin_amdgcn_mfma_f32_32x32x16_f16(kf, qf[dc], z, 0, 0, 0);
      }
      s[mt] = z;
    }
    __builtin_amdgcn_s_setprio(0);

    // ---- tile max (tree) + cross-half combine ----
    float tm[16];
#pragma unroll
    for (int i2 = 0; i2 < 16; ++i2) tm[i2] = fmaxf(s[0][i2], s[1][i2]);
#pragma unroll
    for (int st = 8; st > 0; st >>= 1)
#pragma unroll
      for (int i2 = 0; i2 < st; ++i2) tm[i2] = fmaxf(tm[i2], tm[i2 + st]);
    const float mx = fmaxf(tm[0], __shfl_xor(tm[0], 32));

    // ---- defer-max (T13) ----
    if (__any(mx > m_run + 8.f)) {
      const float mnew = fmaxf(m_run, mx);
      const float corr = __builtin_amdgcn_exp2f(m_run - mnew);
      m_run = mnew;
      l_run *= corr;
#pragma unroll
      for (int mt = 0; mt < 2; ++mt)
#pragma unroll
        for (int r = 0; r < 16; ++r) oa[mt][r] *= corr;
    }
    const float negm = -m_run;

    // ---- p = exp2(s - m); tree sum ----
#pragma unroll
    for (int mt = 0; mt < 2; ++mt)
#pragma unroll
      for (int r = 0; r < 16; ++r)
        s[mt][r] = __builtin_amdgcn_exp2f(s[mt][r] + negm);
    float tsum[16];
#pragma unroll
    for (int i2 = 0; i2 < 16; ++i2) tsum[i2] = s[0][i2] + s[1][i2];
#pragma unroll
    for (int st = 8; st > 0; st >>= 1)
#pragma unroll
      for (int i2 = 0; i2 < st; ++i2) tsum[i2] += tsum[i2 + st];
    l_run += tsum[0] + __shfl_xor(tsum[0], 32);

    // ---- pack P to f16 pairs ----
    u32 pkA[2][4], pkB[2][4];
#pragma unroll
    for (int mt = 0; mt < 2; ++mt)
#pragma unroll
      for (int g = 0; g < 4; ++g) {
        pkA[mt][g] = pkrtz(s[mt][4 * g + 0], s[mt][4 * g + 1]);
        pkB[mt][g] = pkrtz(s[mt][4 * g + 2], s[mt][4 * g + 3]);
      }

    // ---- PV (swapped): oa[md] += V^T * P ----
    __builtin_amdgcn_s_setprio(1);
#pragma unroll
    for (int kk = 0; kk < 4; ++kk) {
      const int e = kk & 1, mt = kk >> 1;
      u32 crossA = __shfl_xor(h ? pkA[mt][2 * e] : pkA[mt][2 * e + 1], 32);
      u32 crossB = __shfl_xor(h ? pkB[mt][2 * e] : pkB[mt][2 * e + 1], 32);
      union { u32 u[4]; f16x8 v; } pb;
      pb.u[0] = h ? crossA : pkA[mt][2 * e];
      pb.u[1] = h ? crossB : pkB[mt][2 * e];
      pb.u[2] = h ? pkA[mt][2 * e + 1] : crossA;
      pb.u[3] = h ? pkB[mt][2 * e + 1] : crossB;
#pragma unroll
      for (int md = 0; md < 2; ++md) {
        f16x8 vf = *(const f16x8*)(vd + paddr(md * 32 + q, kk * 16 + h * 8));
        oa[md] = __builtin_amdgcn_mfma_f32_32x32x16_f16(vf, pb.v, oa[md], 0, 0, 0);
      }
    }
    __builtin_amdgcn_s_setprio(0);

    // ---- write prefetched tile into the other buffer ----
    if (pf) writeT(cur ^ 1);
    __syncthreads();
    cur ^= 1;
  }

  // ---- merge: pair1 publishes unnormalized O + (m,l); pair0 combines ----
  float* O1 = (float*)(smem + 32768);   // [mt*16+r][ (pw*32+q)*2 + h ]
  float* ml1 = (float*)(smem + 49152);  // [pw*32+q][2]
  if (pr == 1) {
#pragma unroll
    for (int mt = 0; mt < 2; ++mt)
#pragma unroll
      for (int r = 0; r < 16; ++r)
        O1[(mt * 16 + r) * 128 + (pw * 32 + q) * 2 + h] = oa[mt][r];
    if (h == 0) *(float2*)(ml1 + (pw * 32 + q) * 2) = make_float2(m_run, l_run);
  }
  __syncthreads();
  float* Os = (float*)smem;  // [64][68]
  if (pr == 0) {
    const float2 m1l1 = *(const float2*)(ml1 + (pw * 32 + q) * 2);
    const float mm = fmaxf(m_run, m1l1.x);
    float w0 = __builtin_amdgcn_exp2f(m_run - mm);
    float w1 = __builtin_amdgcn_exp2f(m1l1.x - mm);
    const float inv = 1.f / (l_run * w0 + m1l1.y * w1);
    w0 *= inv; w1 *= inv;
#pragma unroll
    for (int mt = 0; mt < 2; ++mt)
#pragma unroll
      for (int r = 0; r < 16; ++r) {
        const int d = mt * 32 + (r & 3) + 8 * (r >> 2) + 4 * h;
        const float v1 = O1[(mt * 16 + r) * 128 + (pw * 32 + q) * 2 + h];
        Os[(pw * 32 + q) * 68 + d] = oa[mt][r] * w0 + v1 * w1;
      }
  }
  __syncthreads();
  {
    const int row = tid >> 2, cb = (tid & 3) * 16;
    float* op = O + ((size_t)bh * kS + q0 + row) * kD + cb;
    const float* sp = Os + row * 68 + cb;
#pragma unroll
    for (int j = 0; j < 4; ++j) *(float4*)(op + 4 * j) = *(const float4*)(sp + 4 * j);
  }
}

// ---------------- fallback (round-1 kernel) if ws is too small -------------
__device__ __forceinline__ int swz(int row, int colh) {
  return row * 64 + (colh ^ ((row & 7) << 3));
}

__global__ __launch_bounds__(256, 4) void fattn_fallback(
    const float* __restrict__ Q, const float* __restrict__ K,
    const float* __restrict__ V, const int* __restrict__ M,
    float* __restrict__ O) {
  __shared__ __align__(16) _Float16 Kl[64 * 64];
  __shared__ __align__(16) _Float16 Vtl[64 * 64];
  __shared__ __align__(16) _Float16 Pl[64 * 64];
  __shared__ float mbl[64];

  const int tid = threadIdx.x;
  const int lane = tid & 63;
  const int w = tid >> 6;
  const int lr = lane & 15;
  const int hg = lane >> 4;
  const int NQT1 = kS / 64;
  const int bh = blockIdx.x / NQT1;
  const int qt = blockIdx.x % NQT1;
  const int b = bh / kH;
  const int q0 = qt * 64;

  f16x8 aq[2];
  {
    const int row = q0 + w * 16 + lr;
    const float* qp = Q + ((size_t)bh * kS + row) * kD;
#pragma unroll
    for (int kf = 0; kf < 2; ++kf) {
      const float* p = qp + kf * 32 + hg * 8;
      float4 x = *(const float4*)(p);
      float4 y = *(const float4*)(p + 4);
      f16x8 a;
      a[0] = (_Float16)(x.x * 0.125f); a[1] = (_Float16)(x.y * 0.125f);
      a[2] = (_Float16)(x.z * 0.125f); a[3] = (_Float16)(x.w * 0.125f);
      a[4] = (_Float16)(y.x * 0.125f); a[5] = (_Float16)(y.y * 0.125f);
      a[6] = (_Float16)(y.z * 0.125f); a[7] = (_Float16)(y.w * 0.125f);
      aq[kf] = a;
    }
  }

  f32x4 oacc[4];
#pragma unroll
  for (int c = 0; c < 4; ++c) { oacc[c][0]=0.f; oacc[c][1]=0.f; oacc[c][2]=0.f; oacc[c][3]=0.f; }
  float m_run[4], l_run[4];
#pragma unroll
  for (int r = 0; r < 4; ++r) { m_run[r] = -1e30f; l_run[r] = 0.f; }

  const float* kb = K + (size_t)bh * kS * kD;
  const float* vb = V + (size_t)bh * kS * kD;
  const int* mbp = M + b * kS;

  for (int t0 = 0; t0 < kS; t0 += 64) {
    __syncthreads();
#pragma unroll
    for (int i = 0; i < 4; ++i) {
      const int off = (tid + 256 * i) * 4;
      const int row = off >> 6;
      const int col = off & 63;
      float4 kx = *(const float4*)(kb + (size_t)(t0 + row) * kD + col);
      f16x4 hk;
      hk[0] = (_Float16)kx.x; hk[1] = (_Float16)kx.y;
      hk[2] = (_Float16)kx.z; hk[3] = (_Float16)kx.w;
      *(f16x4*)(Kl + swz(row, col)) = hk;
      float4 vx = *(const float4*)(vb + (size_t)(t0 + row) * kD + col);
      Vtl[swz(col + 0, row)] = (_Float16)vx.x;
      Vtl[swz(col + 1, row)] = (_Float16)vx.y;
      Vtl[swz(col + 2, row)] = (_Float16)vx.z;
      Vtl[swz(col + 3, row)] = (_Float16)vx.w;
    }
    if (tid < 64) mbl[tid] = mbp[t0 + tid] ? 0.f : -1e30f;
    __syncthreads();

    f32x4 s[4];
#pragma unroll
    for (int c = 0; c < 4; ++c) {
      f32x4 z; z[0]=0.f; z[1]=0.f; z[2]=0.f; z[3]=0.f;
#pragma unroll
      for (int kf = 0; kf < 2; ++kf) {
        f16x8 bk = *(const f16x8*)(Kl + swz(c * 16 + lr, kf * 32 + hg * 8));
        z = __builtin_amdgcn_mfma_f32_16x16x32_f16(aq[kf], bk, z, 0, 0, 0);
      }
      const float mval = mbl[c * 16 + lr];
#pragma unroll
      for (int r = 0; r < 4; ++r) z[r] += mval;
      s[c] = z;
    }

    float tmax[4];
#pragma unroll
    for (int r = 0; r < 4; ++r)
      tmax[r] = fmaxf(fmaxf(s[0][r], s[1][r]), fmaxf(s[2][r], s[3][r]));
#pragma unroll
    for (int off = 1; off < 16; off <<= 1)
#pragma unroll
      for (int r = 0; r < 4; ++r) tmax[r] = fmaxf(tmax[r], __shfl_xor(tmax[r], off));

    float mnew[4], corr[4], tsum[4];
#pragma unroll
    for (int r = 0; r < 4; ++r) {
      mnew[r] = fmaxf(m_run[r], tmax[r]);
      corr[r] = __expf(m_run[r] - mnew[r]);
      m_run[r] = mnew[r];
      tsum[r] = 0.f;
    }
#pragma unroll
    for (int c = 0; c < 4; ++c)
#pragma unroll
      for (int r = 0; r < 4; ++r) {
        const float p = __expf(s[c][r] - mnew[r]);
        tsum[r] += p;
        Pl[swz(w * 16 + hg * 4 + r, c * 16 + lr)] = (_Float16)p;
      }
#pragma unroll
    for (int off = 1; off < 16; off <<= 1)
#pragma unroll
      for (int r = 0; r < 4; ++r) tsum[r] += __shfl_xor(tsum[r], off);
#pragma unroll
    for (int r = 0; r < 4; ++r) l_run[r] = l_run[r] * corr[r] + tsum[r];
#pragma unroll
    for (int c = 0; c < 4; ++c)
#pragma unroll
      for (int r = 0; r < 4; ++r) oacc[c][r] *= corr[r];

#pragma unroll
    for (int kf = 0; kf < 2; ++kf) {
      f16x8 pa = *(const f16x8*)(Pl + swz(w * 16 + lr, kf * 32 + hg * 8));
#pragma unroll
      for (int cd = 0; cd < 4; ++cd) {
        f16x8 vbf = *(const f16x8*)(Vtl + swz(cd * 16 + lr, kf * 32 + hg * 8));
        oacc[cd] = __builtin_amdgcn_mfma_f32_16x16x32_f16(pa, vbf, oacc[cd], 0, 0, 0);
      }
    }
  }

#pragma unroll
  for (int r = 0; r < 4; ++r) {
    const float inv = 1.f / l_run[r];
    const int row = q0 + w * 16 + hg * 4 + r;
    float* op = O + ((size_t)bh * kS + row) * kD;
#pragma unroll
    for (int cd = 0; cd < 4; ++cd) op[cd * 16 + lr] = oacc[cd][r] * inv;
  }
}
}  // namespace

extern "C" void kernel_launch(void* const* d_in, const int* in_sizes, int n_in,
                              void* d_out, int out_size, void* d_ws, size_t ws_size,
                              hipStream_t stream) {
  (void)in_sizes; (void)n_in; (void)out_size;
  const float* q = (const float*)d_in[0];
  const float* k = (const float*)d_in[1];
  const float* v = (const float*)d_in[2];
  const int* m = (const int*)d_in[3];
  float* o = (float*)d_out;

  const size_t elems = (size_t)kBH * kS * kD;  // 4.19M
  const size_t need = 2 * elems * sizeof(_Float16)        // Kc + Vtc
                    + (size_t)kB * kS * sizeof(int)       // Idx
                    + (size_t)kB * kS * sizeof(float)     // BiasC
                    + 256;                                // NTarr (padded)

  if (ws_size >= need) {
    _Float16* Kc = (_Float16*)d_ws;
    _Float16* Vtc = Kc + elems;
    int* Idx = (int*)(Vtc + elems);
    float* BiasC = (float*)(Idx + (size_t)kB * kS);
    int* NTarr = (int*)(BiasC + (size_t)kB * kS);
    hipLaunchKernelGGL(scan_kernel, dim3(kB), dim3(256), 0, stream, m, Idx, BiasC, NTarr);
    hipLaunchKernelGGL(gather_k_kernel, dim3((kBH * kS * 8) / 256), dim3(256), 0, stream,
                       k, Idx, NTarr, Kc);
    hipLaunchKernelGGL(gather_vt_kernel, dim3(kBH * (kS / 64)), dim3(256), 0, stream,
                       v, Idx, NTarr, Vtc);
    hipLaunchKernelGGL(fattn_m, dim3(kBH * NQT), dim3(256), 0, stream,
                       Kc, Vtc, q, BiasC, NTarr, o);
  } else {
    hipLaunchKernelGGL(fattn_fallback, dim3(kBH * (kS / 64)), dim3(256), 0, stream,
                       q, k, v, m, o);
  }
}

// Round 12
// 52.346 us; speedup vs baseline: 1.8581x; 1.2045x over previous
//
#include <hip/hip_runtime.h>
#include <hip/hip_fp16.h>

namespace {
constexpr int kB = 2, kH = 16, kS = 2048, kD = 64, kBH = kB * kH;
constexpr int BQ = 128, BKV = 64;
constexpr int NQT = kS / BQ;   // 16

typedef _Float16 f16x8 __attribute__((ext_vector_type(8)));
typedef _Float16 f16x4 __attribute__((ext_vector_type(4)));
typedef __fp16 fp16x2 __attribute__((ext_vector_type(2)));
typedef float f32x16 __attribute__((ext_vector_type(16)));
typedef float f32x4 __attribute__((ext_vector_type(4)));
typedef unsigned int u32;

// Q prescale: 1/sqrt(64) * log2(e) -> softmax done in exp2 domain.
constexpr float kQScale = 0.125f * 1.4426950408889634f;

// Packed LDS tile: 64 logical rows x 64 f16 -> 32 prows x 128 halfwords.
__device__ __forceinline__ int paddr(int row, int col) {
  const int prow = row >> 1;
  return prow * 128 + ((((row & 1) << 6) | col) ^ ((prow & 15) << 3));
}

__device__ __forceinline__ u32 pkrtz(float a, float b) {
  union { fp16x2 h; u32 u; } c;
  c.h = __builtin_amdgcn_cvt_pkrtz(a, b);
  return c.u;
}

// ---- preprocess 1: per-batch mask scan -> compaction index + NT + Nv ----
__global__ __launch_bounds__(256) void scan_kernel(const int* __restrict__ M,
                                                   int* __restrict__ Idx,
                                                   int* __restrict__ NTarr,
                                                   int* __restrict__ Nvarr) {
  const int b = blockIdx.x;
  const int tid = threadIdx.x;
  __shared__ int part[256];
  __shared__ int nvs;
  int m[8], sum = 0;
#pragma unroll
  for (int i = 0; i < 8; ++i) {
    m[i] = M[b * kS + tid * 8 + i];
    sum += m[i] ? 1 : 0;
  }
  part[tid] = sum;
  __syncthreads();
  for (int off = 1; off < 256; off <<= 1) {
    int v = (tid >= off) ? part[tid - off] : 0;
    __syncthreads();
    part[tid] += v;
    __syncthreads();
  }
  int run = part[tid] - sum;  // exclusive prefix
#pragma unroll
  for (int i = 0; i < 8; ++i)
    if (m[i]) Idx[b * kS + run++] = tid * 8 + i;
  if (tid == 255) nvs = part[255];
  __syncthreads();
  const int Nv = nvs;
  int NT = (Nv + 63) >> 6;
  if (NT == 0) NT = 1;
  const int pad = NT * 64;
  for (int j = Nv + tid; j < pad; j += 256) Idx[b * kS + j] = 0;
  if (tid == 0) { NTarr[b] = NT; Nvarr[b] = Nv; }
}

// ---- preprocess 2 (fused): gather K -> f16 [bh][j][d] and V -> f16^T
// [bh][d][j], one block per (bh, key-tile). ----
__global__ __launch_bounds__(256) void gather_kv_kernel(
    const float* __restrict__ K, const float* __restrict__ V,
    const int* __restrict__ Idx, const int* __restrict__ NTarr,
    _Float16* __restrict__ Kc, _Float16* __restrict__ Vtc) {
  __shared__ _Float16 Vl[64 * 68];
  __shared__ int ridx[64];
  const int tid = threadIdx.x;
  const int bh = blockIdx.x >> 5;
  const int jt = blockIdx.x & 31;
  const int b = bh >> 4;
  if (jt >= NTarr[b]) return;
  if (tid < 64) ridx[tid] = Idx[b * kS + jt * 64 + tid];
  __syncthreads();

  // K gather: 512 (row, 8-col) granules over 2 iters; coalesced per row.
  const float* kbase = K + (size_t)bh * kS * kD;
  _Float16* kout = Kc + ((size_t)bh * kS + jt * 64) * kD;
#pragma unroll
  for (int it = 0; it < 2; ++it) {
    const int e = tid + 256 * it;
    const int row = e >> 3, d0 = (e & 7) * 8;
    const float* p = kbase + (size_t)ridx[row] * kD + d0;
    float4 x = *(const float4*)p;
    float4 y = *(const float4*)(p + 4);
    f16x8 o;
    o[0] = (_Float16)x.x; o[1] = (_Float16)x.y; o[2] = (_Float16)x.z; o[3] = (_Float16)x.w;
    o[4] = (_Float16)y.x; o[5] = (_Float16)y.y; o[6] = (_Float16)y.z; o[7] = (_Float16)y.w;
    *(f16x8*)(kout + (size_t)row * kD + d0) = o;
  }

  // V gather + transpose via LDS.
  const float* vb = V + (size_t)bh * kS * kD;
#pragma unroll
  for (int i = 0; i < 4; ++i) {
    int off = (tid + 256 * i) * 4;
    int r = off >> 6, c = off & 63;
    float4 x = *(const float4*)(vb + (size_t)ridx[r] * kD + c);
    Vl[(c + 0) * 68 + r] = (_Float16)x.x;
    Vl[(c + 1) * 68 + r] = (_Float16)x.y;
    Vl[(c + 2) * 68 + r] = (_Float16)x.z;
    Vl[(c + 3) * 68 + r] = (_Float16)x.w;
  }
  __syncthreads();
  const int d = tid >> 2, c0 = (tid & 3) * 16;
  _Float16* op = Vtc + ((size_t)bh * kD + d) * kS + jt * 64 + c0;
#pragma unroll
  for (int j = 0; j < 4; ++j)
    *(f16x4*)(op + 4 * j) = *(const f16x4*)(Vl + d * 68 + c0 + 4 * j);
}

// ------- main: 32x32 swapped flash attention over COMPACTED keys -------
// R9 structure; bias-free hot loop (zero C-init, pad-mask via predicated
// VALU on the LAST tile only).
__global__ __launch_bounds__(256, 2) void fattn_c(
    const _Float16* __restrict__ Kc, const _Float16* __restrict__ Vtc,
    const float* __restrict__ Q, const int* __restrict__ NTarr,
    const int* __restrict__ Nvarr, float* __restrict__ O) {
  // K dbuf 16K | V dbuf 16K ; epilogue Os overlays the front.
  __shared__ __align__(16) char smem[32768];
  _Float16* Kl = (_Float16*)smem;            // [2][32*128]
  _Float16* Vl = (_Float16*)(smem + 16384);  // [2][32*128]
  float* Os = (float*)smem;                  // overlay [64][68]

  const int tid = threadIdx.x;
  const int lane = tid & 63;
  const int w = tid >> 6;    // wave 0..3
  const int q = lane & 31;   // qrow within wave tile
  const int h = lane >> 5;   // half 0/1

  // XCD-aware bijective swizzle (gridDim = 512, %8 == 0).
  const int bid = blockIdx.x;
  const int cpx = gridDim.x >> 3;
  const int sbid = (bid & 7) * cpx + (bid >> 3);
  const int bh = sbid >> 4;
  const int qt = sbid & 15;
  const int q0 = qt * BQ;
  const int b = bh >> 4;  // H=16
  const int NT = NTarr[b];
  const int Nv = Nvarr[b];

  // Q fragments (B-operand), pre-scaled into exp2 domain.
  f16x8 qf[4];
  {
    const float* qp = Q + ((size_t)bh * kS + q0 + w * 32 + q) * kD;
#pragma unroll
    for (int dc = 0; dc < 4; ++dc) {
      const float* p = qp + dc * 16 + h * 8;
      float4 x = *(const float4*)p;
      float4 y = *(const float4*)(p + 4);
      f16x8 a;
      a[0] = (_Float16)(x.x * kQScale); a[1] = (_Float16)(x.y * kQScale);
      a[2] = (_Float16)(x.z * kQScale); a[3] = (_Float16)(x.w * kQScale);
      a[4] = (_Float16)(y.x * kQScale); a[5] = (_Float16)(y.y * kQScale);
      a[6] = (_Float16)(y.z * kQScale); a[7] = (_Float16)(y.w * kQScale);
      qf[dc] = a;
    }
  }

  f32x16 oa[2];
#pragma unroll
  for (int i = 0; i < 16; ++i) { oa[0][i] = 0.f; oa[1][i] = 0.f; }
  f32x16 kZero;
#pragma unroll
  for (int i = 0; i < 16; ++i) kZero[i] = 0.f;
  float m_run = -30.f, l_run = 0.f;

  const _Float16* kb = Kc + (size_t)bh * kS * kD;
  const _Float16* vb = Vtc + (size_t)bh * kD * kS;

  // staging geometry: thread -> (row = tid>>2, colbase = (tid&3)*16)
  const int sr = tid >> 2, sc = (tid & 3) * 16;
  const int a0 = paddr(sr, sc), a1 = paddr(sr, sc + 8);

  // prologue stage tile 0 into buf 0
  {
    f16x8 k0 = *(const f16x8*)(kb + (size_t)sr * kD + sc);
    f16x8 k1 = *(const f16x8*)(kb + (size_t)sr * kD + sc + 8);
    f16x8 v0 = *(const f16x8*)(vb + (size_t)sr * kS + sc);
    f16x8 v1 = *(const f16x8*)(vb + (size_t)sr * kS + sc + 8);
    *(f16x8*)(Kl + a0) = k0; *(f16x8*)(Kl + a1) = k1;
    *(f16x8*)(Vl + a0) = v0; *(f16x8*)(Vl + a1) = v1;
  }
  __syncthreads();

  int cur = 0;
  for (int t = 0; t < NT; ++t) {
    const int t0 = t * BKV;
    const bool pf = (t + 1 < NT);
    // ---- T14: issue next-tile global loads before compute ----
    f16x8 nk0, nk1, nv0, nv1;
    if (pf) {
      const int n0 = t0 + BKV;
      nk0 = *(const f16x8*)(kb + (size_t)(n0 + sr) * kD + sc);
      nk1 = *(const f16x8*)(kb + (size_t)(n0 + sr) * kD + sc + 8);
      nv0 = *(const f16x8*)(vb + (size_t)sr * kS + n0 + sc);
      nv1 = *(const f16x8*)(vb + (size_t)sr * kS + n0 + sc + 8);
    }

    const _Float16* kd = Kl + cur * 4096;
    const _Float16* vd = Vl + cur * 4096;

    // ---- QK^T (swapped), zero C-init (compacted keys need no bias) ----
    // s[mt][4g+j] has key = t*64 + mt*32 + 8g + 4h + j, qrow = q
    f32x16 s[2];
    __builtin_amdgcn_s_setprio(1);
#pragma unroll
    for (int mt = 0; mt < 2; ++mt) {
      f32x16 z = kZero;
#pragma unroll
      for (int dc = 0; dc < 4; ++dc) {
        f16x8 kf = *(const f16x8*)(kd + paddr(mt * 32 + q, dc * 16 + h * 8));
        z = __builtin_amdgcn_mfma_f32_32x32x16_f16(kf, qf[dc], z, 0, 0, 0);
      }
      s[mt] = z;
    }
    __builtin_amdgcn_s_setprio(0);

    // ---- pad-mask: LAST tile only, pure VALU (key >= Nv -> -1e30) ----
    if (t == NT - 1) {
      const int kbase = t0 + 4 * h;
#pragma unroll
      for (int mt = 0; mt < 2; ++mt)
#pragma unroll
        for (int r = 0; r < 16; ++r) {
          const int key = kbase + mt * 32 + 8 * (r >> 2) + (r & 3);
          if (key >= Nv) s[mt][r] = -1e30f;
        }
    }

    // ---- tile max (tree) + cross-half combine ----
    float tm[16];
#pragma unroll
    for (int i = 0; i < 16; ++i) tm[i] = fmaxf(s[0][i], s[1][i]);
#pragma unroll
    for (int st = 8; st > 0; st >>= 1)
#pragma unroll
      for (int i = 0; i < st; ++i) tm[i] = fmaxf(tm[i], tm[i + st]);
    const float mx = fmaxf(tm[0], __shfl_xor(tm[0], 32));

    // ---- defer-max (T13): only rescale when max grew by > 8 (log2) ----
    if (__any(mx > m_run + 8.f)) {
      const float mnew = fmaxf(m_run, mx);
      const float corr = __builtin_amdgcn_exp2f(m_run - mnew);
      m_run = mnew;
      l_run *= corr;
#pragma unroll
      for (int mt = 0; mt < 2; ++mt)
#pragma unroll
        for (int r = 0; r < 16; ++r) oa[mt][r] *= corr;
    }
    const float negm = -m_run;

    // ---- p = exp2(s - m); tree sum ----
#pragma unroll
    for (int mt = 0; mt < 2; ++mt)
#pragma unroll
      for (int r = 0; r < 16; ++r)
        s[mt][r] = __builtin_amdgcn_exp2f(s[mt][r] + negm);
    float tsum[16];
#pragma unroll
    for (int i = 0; i < 16; ++i) tsum[i] = s[0][i] + s[1][i];
#pragma unroll
    for (int st = 8; st > 0; st >>= 1)
#pragma unroll
      for (int i = 0; i < st; ++i) tsum[i] += tsum[i + st];
    l_run += tsum[0] + __shfl_xor(tsum[0], 32);

    // ---- pack P to f16 pairs ----
    u32 pkA[2][4], pkB[2][4];
#pragma unroll
    for (int mt = 0; mt < 2; ++mt)
#pragma unroll
      for (int g = 0; g < 4; ++g) {
        pkA[mt][g] = pkrtz(s[mt][4 * g + 0], s[mt][4 * g + 1]);
        pkB[mt][g] = pkrtz(s[mt][4 * g + 2], s[mt][4 * g + 3]);
      }

    // ---- PV (swapped): oa[md] += V^T * P ; B-frag built in-register ----
    __builtin_amdgcn_s_setprio(1);
#pragma unroll
    for (int kk = 0; kk < 4; ++kk) {
      const int e = kk & 1, mt = kk >> 1;
      u32 crossA = __shfl_xor(h ? pkA[mt][2 * e] : pkA[mt][2 * e + 1], 32);
      u32 crossB = __shfl_xor(h ? pkB[mt][2 * e] : pkB[mt][2 * e + 1], 32);
      union { u32 u[4]; f16x8 v; } pb;
      pb.u[0] = h ? crossA : pkA[mt][2 * e];
      pb.u[1] = h ? crossB : pkB[mt][2 * e];
      pb.u[2] = h ? pkA[mt][2 * e + 1] : crossA;
      pb.u[3] = h ? pkB[mt][2 * e + 1] : crossB;
#pragma unroll
      for (int md = 0; md < 2; ++md) {
        f16x8 vf = *(const f16x8*)(vd + paddr(md * 32 + q, kk * 16 + h * 8));
        oa[md] = __builtin_amdgcn_mfma_f32_32x32x16_f16(vf, pb.v, oa[md], 0, 0, 0);
      }
    }
    __builtin_amdgcn_s_setprio(0);

    // ---- write prefetched tile into the other buffer ----
    if (pf) {
      _Float16* kd2 = Kl + (cur ^ 1) * 4096;
      _Float16* vd2 = Vl + (cur ^ 1) * 4096;
      *(f16x8*)(kd2 + a0) = nk0; *(f16x8*)(kd2 + a1) = nk1;
      *(f16x8*)(vd2 + a0) = nv0; *(f16x8*)(vd2 + a1) = nv1;
    }
    __syncthreads();
    cur ^= 1;
  }

  // ---- epilogue: normalize, transpose via LDS, coalesced store ----
  const float inv = 1.f / l_run;
#pragma unroll
  for (int ph = 0; ph < 2; ++ph) {
    __syncthreads();
    if ((w >> 1) == ph) {
#pragma unroll
      for (int mt = 0; mt < 2; ++mt)
#pragma unroll
        for (int r = 0; r < 16; ++r) {
          int d = mt * 32 + (r & 3) + 8 * (r >> 2) + 4 * h;
          Os[((w & 1) * 32 + q) * 68 + d] = oa[mt][r] * inv;
        }
    }
    __syncthreads();
    {
      const int row = tid >> 2, cb = (tid & 3) * 16;
      float* op = O + ((size_t)bh * kS + q0 + ph * 64 + row) * kD + cb;
      const float* sp = Os + row * 68 + cb;
#pragma unroll
      for (int j = 0; j < 4; ++j) *(float4*)(op + 4 * j) = *(const float4*)(sp + 4 * j);
    }
  }
}

// ---------------- fallback (round-1 kernel) if ws is too small -------------
__device__ __forceinline__ int swz(int row, int colh) {
  return row * 64 + (colh ^ ((row & 7) << 3));
}

__global__ __launch_bounds__(256, 4) void fattn_fallback(
    const float* __restrict__ Q, const float* __restrict__ K,
    const float* __restrict__ V, const int* __restrict__ M,
    float* __restrict__ O) {
  __shared__ __align__(16) _Float16 Kl[64 * 64];
  __shared__ __align__(16) _Float16 Vtl[64 * 64];
  __shared__ __align__(16) _Float16 Pl[64 * 64];
  __shared__ float mbl[64];

  const int tid = threadIdx.x;
  const int lane = tid & 63;
  const int w = tid >> 6;
  const int lr = lane & 15;
  const int hg = lane >> 4;
  const int NQT1 = kS / 64;
  const int bh = blockIdx.x / NQT1;
  const int qt = blockIdx.x % NQT1;
  const int b = bh / kH;
  const int q0 = qt * 64;

  f16x8 aq[2];
  {
    const int row = q0 + w * 16 + lr;
    const float* qp = Q + ((size_t)bh * kS + row) * kD;
#pragma unroll
    for (int kf = 0; kf < 2; ++kf) {
      const float* p = qp + kf * 32 + hg * 8;
      float4 x = *(const float4*)(p);
      float4 y = *(const float4*)(p + 4);
      f16x8 a;
      a[0] = (_Float16)(x.x * 0.125f); a[1] = (_Float16)(x.y * 0.125f);
      a[2] = (_Float16)(x.z * 0.125f); a[3] = (_Float16)(x.w * 0.125f);
      a[4] = (_Float16)(y.x * 0.125f); a[5] = (_Float16)(y.y * 0.125f);
      a[6] = (_Float16)(y.z * 0.125f); a[7] = (_Float16)(y.w * 0.125f);
      aq[kf] = a;
    }
  }

  f32x4 oacc[4];
#pragma unroll
  for (int c = 0; c < 4; ++c) { oacc[c][0]=0.f; oacc[c][1]=0.f; oacc[c][2]=0.f; oacc[c][3]=0.f; }
  float m_run[4], l_run[4];
#pragma unroll
  for (int r = 0; r < 4; ++r) { m_run[r] = -1e30f; l_run[r] = 0.f; }

  const float* kb = K + (size_t)bh * kS * kD;
  const float* vb = V + (size_t)bh * kS * kD;
  const int* mbp = M + b * kS;

  for (int t0 = 0; t0 < kS; t0 += 64) {
    __syncthreads();
#pragma unroll
    for (int i = 0; i < 4; ++i) {
      const int off = (tid + 256 * i) * 4;
      const int row = off >> 6;
      const int col = off & 63;
      float4 kx = *(const float4*)(kb + (size_t)(t0 + row) * kD + col);
      f16x4 hk;
      hk[0] = (_Float16)kx.x; hk[1] = (_Float16)kx.y;
      hk[2] = (_Float16)kx.z; hk[3] = (_Float16)kx.w;
      *(f16x4*)(Kl + swz(row, col)) = hk;
      float4 vx = *(const float4*)(vb + (size_t)(t0 + row) * kD + col);
      Vtl[swz(col + 0, row)] = (_Float16)vx.x;
      Vtl[swz(col + 1, row)] = (_Float16)vx.y;
      Vtl[swz(col + 2, row)] = (_Float16)vx.z;
      Vtl[swz(col + 3, row)] = (_Float16)vx.w;
    }
    if (tid < 64) mbl[tid] = mbp[t0 + tid] ? 0.f : -1e30f;
    __syncthreads();

    f32x4 s[4];
#pragma unroll
    for (int c = 0; c < 4; ++c) {
      f32x4 z; z[0]=0.f; z[1]=0.f; z[2]=0.f; z[3]=0.f;
#pragma unroll
      for (int kf = 0; kf < 2; ++kf) {
        f16x8 bk = *(const f16x8*)(Kl + swz(c * 16 + lr, kf * 32 + hg * 8));
        z = __builtin_amdgcn_mfma_f32_16x16x32_f16(aq[kf], bk, z, 0, 0, 0);
      }
      const float mval = mbl[c * 16 + lr];
#pragma unroll
      for (int r = 0; r < 4; ++r) z[r] += mval;
      s[c] = z;
    }

    float tmax[4];
#pragma unroll
    for (int r = 0; r < 4; ++r)
      tmax[r] = fmaxf(fmaxf(s[0][r], s[1][r]), fmaxf(s[2][r], s[3][r]));
#pragma unroll
    for (int off = 1; off < 16; off <<= 1)
#pragma unroll
      for (int r = 0; r < 4; ++r) tmax[r] = fmaxf(tmax[r], __shfl_xor(tmax[r], off));

    float mnew[4], corr[4], tsum[4];
#pragma unroll
    for (int r = 0; r < 4; ++r) {
      mnew[r] = fmaxf(m_run[r], tmax[r]);
      corr[r] = __expf(m_run[r] - mnew[r]);
      m_run[r] = mnew[r];
      tsum[r] = 0.f;
    }
#pragma unroll
    for (int c = 0; c < 4; ++c)
#pragma unroll
      for (int r = 0; r < 4; ++r) {
        const float p = __expf(s[c][r] - mnew[r]);
        tsum[r] += p;
        Pl[swz(w * 16 + hg * 4 + r, c * 16 + lr)] = (_Float16)p;
      }
#pragma unroll
    for (int off = 1; off < 16; off <<= 1)
#pragma unroll
      for (int r = 0; r < 4; ++r) tsum[r] += __shfl_xor(tsum[r], off);
#pragma unroll
    for (int r = 0; r < 4; ++r) l_run[r] = l_run[r] * corr[r] + tsum[r];
#pragma unroll
    for (int c = 0; c < 4; ++c)
#pragma unroll
      for (int r = 0; r < 4; ++r) oacc[c][r] *= corr[r];

#pragma unroll
    for (int kf = 0; kf < 2; ++kf) {
      f16x8 pa = *(const f16x8*)(Pl + swz(w * 16 + lr, kf * 32 + hg * 8));
#pragma unroll
      for (int cd = 0; cd < 4; ++cd) {
        f16x8 vbf = *(const f16x8*)(Vtl + swz(cd * 16 + lr, kf * 32 + hg * 8));
        oacc[cd] = __builtin_amdgcn_mfma_f32_16x16x32_f16(pa, vbf, oacc[cd], 0, 0, 0);
      }
    }
  }

#pragma unroll
  for (int r = 0; r < 4; ++r) {
    const float inv = 1.f / l_run[r];
    const int row = q0 + w * 16 + hg * 4 + r;
    float* op = O + ((size_t)bh * kS + row) * kD;
#pragma unroll
    for (int cd = 0; cd < 4; ++cd) op[cd * 16 + lr] = oacc[cd][r] * inv;
  }
}
}  // namespace

extern "C" void kernel_launch(void* const* d_in, const int* in_sizes, int n_in,
                              void* d_out, int out_size, void* d_ws, size_t ws_size,
                              hipStream_t stream) {
  (void)in_sizes; (void)n_in; (void)out_size;
  const float* q = (const float*)d_in[0];
  const float* k = (const float*)d_in[1];
  const float* v = (const float*)d_in[2];
  const int* m = (const int*)d_in[3];
  float* o = (float*)d_out;

  const size_t elems = (size_t)kBH * kS * kD;  // 4.19M
  const size_t need = 2 * elems * sizeof(_Float16)    // Kc + Vtc
                    + (size_t)kB * kS * sizeof(int)   // Idx
                    + 512;                            // NTarr + Nvarr

  if (ws_size >= need) {
    _Float16* Kc = (_Float16*)d_ws;
    _Float16* Vtc = Kc + elems;
    int* Idx = (int*)(Vtc + elems);
    int* NTarr = Idx + (size_t)kB * kS;
    int* Nvarr = NTarr + 64;
    hipLaunchKernelGGL(scan_kernel, dim3(kB), dim3(256), 0, stream, m, Idx, NTarr, Nvarr);
    hipLaunchKernelGGL(gather_kv_kernel, dim3(kBH * (kS / 64)), dim3(256), 0, stream,
                       k, v, Idx, NTarr, Kc, Vtc);
    hipLaunchKernelGGL(fattn_c, dim3(kBH * NQT), dim3(256), 0, stream,
                       Kc, Vtc, q, NTarr, Nvarr, o);
  } else {
    hipLaunchKernelGGL(fattn_fallback, dim3(kBH * (kS / 64)), dim3(256), 0, stream,
                       q, k, v, m, o);
  }
}